// Round 2
// baseline (205.392 us; speedup 1.0000x reference)
//
#include <hip/hip_runtime.h>
#include <hip/hip_bf16.h>

#define NBANK 32
#define DHEAD 128
#define DMODEL 2048
#define NSLOT 8192   // B*S*K = 2*1024*4
#define NTOK 2048    // B*S

typedef __attribute__((ext_vector_type(8))) short short8;
typedef __attribute__((ext_vector_type(4))) float f32x4;

__device__ __forceinline__ unsigned short f2bf(float f) {
    union { __hip_bfloat16 h; unsigned short u; } cvt;
    cvt.h = __float2bfloat16(f);
    return cvt.u;
}

// Convert W (fp32, [32][128][2048]) -> bf16 in FRAGMENT-SWIZZLED layout:
//   wfrag[(((bank*128 + mt)*4 + kk)*64 + lane)*8 + v]
// holds W[bank][k][m] with m = mt*16 + (lane&15), k = kk*32 + (lane>>4)*8 + v.
// This is exactly the 16x16x32 MFMA B-fragment order, so the GEMM preload is
// one contiguous short8 (16 B) per lane per fragment.
__global__ void convW_kernel(const float* __restrict__ W,
                             unsigned short* __restrict__ wfrag) {
    int t = blockIdx.x * 256 + threadIdx.x;   // one thread per (bank,mt,kk,lane)
    int lane = t & 63;
    int kk = (t >> 6) & 3;
    int mt = (t >> 8) & 127;
    int bank = t >> 15;
    int m = mt * 16 + (lane & 15);
    int kbase = kk * 32 + (lane >> 4) * 8;
    const float* src = W + ((size_t)bank * DHEAD + kbase) * DMODEL + m;
    short8 o;
    #pragma unroll
    for (int v = 0; v < 8; ++v)
        o[v] = (short)f2bf(src[v * DMODEL]);
    reinterpret_cast<short8*>(wfrag)[t] = o;
}

// Per slot: xbf[slot][:] = bf16(p[slot] * x[slot][:]); append slot to its
// bank's list. One wave per slot (64 lanes x 2 floats = 128).
__global__ void bucket_kernel(const float* __restrict__ x,
                              const int* __restrict__ sel,
                              const float* __restrict__ probs,
                              unsigned short* __restrict__ xbf,
                              int* __restrict__ counts,
                              int* __restrict__ lists) {
    int tid = threadIdx.x;
    int slot = blockIdx.x * 4 + (tid >> 6);
    int lane = tid & 63;
    float p = probs[slot];
    float2 v = reinterpret_cast<const float2*>(x + slot * DHEAD)[lane];
    ushort2 o;
    o.x = f2bf(v.x * p);
    o.y = f2bf(v.y * p);
    reinterpret_cast<ushort2*>(xbf + slot * DHEAD)[lane] = o;
    if (lane == 0) {
        int bank = sel[slot];
        int pos = atomicAdd(&counts[bank], 1);
        lists[bank * NSLOT + pos] = slot;
    }
}

// Grouped GEMM: grid = (m-tiles=16, banks=32, row-split=4), 256 threads.
// Per block: bank fixed, 128-wide m-tile. W fragments preloaded via coalesced
// short8 loads from the fragment-swizzled layout. Row-tiles of 16 gathered
// x-rows stream through a 4 KB XOR-swizzled LDS tile. Epilogue scatters with
// atomicAdd (folds the k-merge; each slot is in exactly one bank list).
__global__ __launch_bounds__(256, 4)
void gemm_kernel(const unsigned short* __restrict__ wfrag,
                 const unsigned short* __restrict__ xbf,
                 const int* __restrict__ counts,
                 const int* __restrict__ lists,
                 const float* __restrict__ probs,
                 const float* __restrict__ bias,
                 float* __restrict__ out) {
    __shared__ __align__(16) unsigned short A_lds[16 * DHEAD]; // 4 KB
    __shared__ int slots_lds[16];

    int tid = threadIdx.x;
    int w = tid >> 6;          // wave 0..3
    int lane = tid & 63;
    int lane_lo = lane & 15;   // MFMA: A row / B col / D col
    int lane_hi = lane >> 4;   // MFMA: k-group / D row-group
    int bank = blockIdx.y;
    int m0 = blockIdx.x * 128;
    int mw = m0 + w * 32;      // this wave's 32-col m-slice
    int mt0 = mw >> 4;         // first 16-col tile index
    int cnt = counts[bank];

    // ---- Preload W fragments: 8 coalesced 16B loads per lane ----
    const short8* wf = reinterpret_cast<const short8*>(wfrag);
    short8 bw[4][2];
    #pragma unroll
    for (int nf = 0; nf < 2; ++nf)
        #pragma unroll
        for (int kk = 0; kk < 4; ++kk)
            bw[kk][nf] = wf[((((bank * 128 + mt0 + nf) * 4) + kk) << 6) + lane];

    float bias0 = bias[bank * DMODEL + mw + lane_lo];
    float bias1 = bias[bank * DMODEL + mw + 16 + lane_lo];

    for (int rt = blockIdx.z; rt * 16 < cnt; rt += gridDim.z) {
        __syncthreads();   // protect previous iter's A_lds/slots_lds readers
        {
            // 256 threads: thread t loads 16B chunk (t&15) of gathered row (t>>4).
            int row = tid >> 4, chunk = tid & 15;
            int ridx = rt * 16 + row;
            int slot = (ridx < cnt) ? lists[bank * NSLOT + ridx] : -1;
            if (chunk == 0) slots_lds[row] = slot;
            uint4 val = make_uint4(0, 0, 0, 0);
            if (slot >= 0)
                val = reinterpret_cast<const uint4*>(xbf + slot * DHEAD)[chunk];
            int byteoff = row * 256 + ((chunk * 16) ^ ((row & 7) << 4)); // XOR swizzle
            *reinterpret_cast<uint4*>(reinterpret_cast<char*>(A_lds) + byteoff) = val;
        }
        __syncthreads();

        f32x4 acc0 = {0.f, 0.f, 0.f, 0.f};
        f32x4 acc1 = {0.f, 0.f, 0.f, 0.f};
        #pragma unroll
        for (int kk = 0; kk < 4; ++kk) {
            // A-frag: row = lane&15, k = kk*32 + 8*(lane>>4) + v -> 16B contiguous.
            int row = lane_lo;
            int byteoff = row * 256 + ((kk * 64 + lane_hi * 16) ^ ((row & 7) << 4));
            short8 a = *reinterpret_cast<const short8*>(
                reinterpret_cast<char*>(A_lds) + byteoff);
            acc0 = __builtin_amdgcn_mfma_f32_16x16x32_bf16(a, bw[kk][0], acc0, 0, 0, 0);
            acc1 = __builtin_amdgcn_mfma_f32_16x16x32_bf16(a, bw[kk][1], acc1, 0, 0, 0);
        }

        // Epilogue: D[row][col], col = lane&15, row = 4*(lane>>4)+v.
        #pragma unroll
        for (int v = 0; v < 4; ++v) {
            int row = lane_hi * 4 + v;
            int slot = slots_lds[row];
            if (slot >= 0) {
                float pv = probs[slot];
                int obase = (slot >> 2) * DMODEL;   // token = slot / K
                atomicAdd(&out[obase + mw + lane_lo],      acc0[v] + pv * bias0);
                atomicAdd(&out[obase + mw + 16 + lane_lo], acc1[v] + pv * bias1);
            }
        }
    }
}

extern "C" void kernel_launch(void* const* d_in, const int* in_sizes, int n_in,
                              void* d_out, int out_size, void* d_ws, size_t ws_size,
                              hipStream_t stream) {
    const float* x     = (const float*)d_in[0];  // (2,1024,4,128)
    const int*   sel   = (const int*)  d_in[1];  // (2,1024,4)
    const float* probs = (const float*)d_in[2];  // (2,1024,4)
    const float* W     = (const float*)d_in[3];  // (32,128,2048)
    const float* bias  = (const float*)d_in[4];  // (32,2048)
    float* out = (float*)d_out;                  // (2,1024,2048) fp32

    // ws layout (≈19.9 MB total):
    //   [0,128)            counts (32 ints, zeroed each call)
    //   [1024, 1049600)    lists  (32 x 8192 ints)
    //   [1049600, 3146752) xbf    (8192 x 128 bf16, p-scaled)
    //   [3146752, 19923968) wfrag (32 x 128 x 2048 bf16, fragment-swizzled)
    char* ws = (char*)d_ws;
    int* counts = (int*)ws;
    int* lists  = (int*)(ws + 1024);
    unsigned short* xbf   = (unsigned short*)(ws + 1049600);
    unsigned short* wfrag = (unsigned short*)(ws + 3146752);

    hipMemsetAsync(counts, 0, 1024, stream);
    hipMemsetAsync(d_out, 0, (size_t)out_size * sizeof(float), stream);
    convW_kernel<<<4096, 256, 0, stream>>>(W, wfrag);   // 1M threads, 1 frag each
    bucket_kernel<<<2048, 256, 0, stream>>>(x, sel, probs, xbf, counts, lists);
    gemm_kernel<<<dim3(16, 32, 4), 256, 0, stream>>>(wfrag, xbf, counts, lists,
                                                     probs, bias, out);
}

// Round 3
// 128.253 us; speedup vs baseline: 1.6015x; 1.6015x over previous
//
#include <hip/hip_runtime.h>
#include <hip/hip_bf16.h>

#define NBANK 32
#define DHEAD 128
#define DMODEL 2048
#define NSLOT 8192   // B*S*K = 2*1024*4
#define NTOK 2048    // B*S

typedef __attribute__((ext_vector_type(8))) short short8;
typedef __attribute__((ext_vector_type(8))) float float8;
typedef __attribute__((ext_vector_type(4))) float f32x4;

__device__ __forceinline__ unsigned short f2bf(float f) {
    union { __hip_bfloat16 h; unsigned short u; } cvt;
    cvt.h = __float2bfloat16(f);
    return cvt.u;
}
__device__ __forceinline__ float bf2f(unsigned short u) {
    union { float f; unsigned int v; } cvt;
    cvt.v = ((unsigned int)u) << 16;
    return cvt.f;
}

// Convert W (fp32, [32][128][2048]) -> bf16 in FRAGMENT-SWIZZLED layout:
//   wfrag[(((bank*128 + mt)*4 + kk)*64 + lane)*8 + v]
// holds W[bank][k][m] with m = mt*16 + (lane&15), k = kk*32 + (lane>>4)*8 + v.
__global__ void convW_kernel(const float* __restrict__ W,
                             unsigned short* __restrict__ wfrag) {
    int t = blockIdx.x * 256 + threadIdx.x;   // one thread per (bank,mt,kk,lane)
    int lane = t & 63;
    int kk = (t >> 6) & 3;
    int mt = (t >> 8) & 127;
    int bank = t >> 15;
    int m = mt * 16 + (lane & 15);
    int kbase = kk * 32 + (lane >> 4) * 8;
    const float* src = W + ((size_t)bank * DHEAD + kbase) * DMODEL + m;
    short8 o;
    #pragma unroll
    for (int v = 0; v < 8; ++v)
        o[v] = (short)f2bf(src[v * DMODEL]);
    reinterpret_cast<short8*>(wfrag)[t] = o;
}

// Bucket slots by bank with LDS pre-aggregation: 32 blocks x 256 slots.
// 32 LDS-histogram atomics per thread-block -> only 32x32=1024 global atomics
// (vs 8192 same-cacheline atomics before).
__global__ void bucket_kernel(const int* __restrict__ sel,
                              int* __restrict__ counts,
                              int* __restrict__ lists) {
    __shared__ int lcount[NBANK];
    __shared__ int lbase[NBANK];
    int tid = threadIdx.x;
    int slot = blockIdx.x * 256 + tid;
    if (tid < NBANK) lcount[tid] = 0;
    __syncthreads();
    int bank = sel[slot];
    int mypos = atomicAdd(&lcount[bank], 1);
    __syncthreads();
    if (tid < NBANK) lbase[tid] = atomicAdd(&counts[tid], lcount[tid]);
    __syncthreads();
    lists[bank * NSLOT + lbase[bank] + mypos] = slot;
}

// Grouped GEMM: grid = (m-tiles=16, banks=32, row-split=4), 256 threads.
// A-staging gathers fp32 x rows, scales by p, converts to bf16 into a
// XOR-swizzled LDS tile. W fragments from the fragment-swizzled bf16 layout.
// Output: per-slot proj rows (bf16) -- exclusive ownership, NO atomics.
__global__ __launch_bounds__(256, 4)
void gemm_kernel(const unsigned short* __restrict__ wfrag,
                 const float* __restrict__ x,
                 const int* __restrict__ counts,
                 const int* __restrict__ lists,
                 const float* __restrict__ probs,
                 unsigned short* __restrict__ proj) {
    __shared__ __align__(16) unsigned short A_lds[16 * DHEAD]; // 4 KB
    __shared__ int slots_lds[16];

    int tid = threadIdx.x;
    int w = tid >> 6;          // wave 0..3
    int lane = tid & 63;
    int lane_lo = lane & 15;   // MFMA: A row / B col / D col
    int lane_hi = lane >> 4;   // MFMA: k-group / D row-group
    int bank = blockIdx.y;
    int mw = blockIdx.x * 128 + w * 32;  // this wave's 32-col m-slice
    int mt0 = mw >> 4;                   // first 16-col tile index
    int cnt = counts[bank];

    // ---- Preload W fragments: 8 coalesced 16B loads per lane ----
    const short8* wf = reinterpret_cast<const short8*>(wfrag);
    short8 bw[4][2];
    #pragma unroll
    for (int nf = 0; nf < 2; ++nf)
        #pragma unroll
        for (int kk = 0; kk < 4; ++kk)
            bw[kk][nf] = wf[((((bank * 128 + mt0 + nf) * 4) + kk) << 6) + lane];

    for (int rt = blockIdx.z; rt * 16 < cnt; rt += gridDim.z) {
        __syncthreads();   // protect previous iter's A_lds/slots_lds readers
        {
            // thread t: 32B fp32 chunk (t&15) of gathered row (t>>4);
            // scale by p, cvt to bf16, store 16B swizzled.
            int row = tid >> 4, chunk = tid & 15;
            int ridx = rt * 16 + row;
            int slot = (ridx < cnt) ? lists[bank * NSLOT + ridx] : -1;
            if (chunk == 0) slots_lds[row] = slot;
            short8 a = {0, 0, 0, 0, 0, 0, 0, 0};
            if (slot >= 0) {
                float p = probs[slot];
                float8 xv = reinterpret_cast<const float8*>(x + (size_t)slot * DHEAD)[chunk];
                #pragma unroll
                for (int j = 0; j < 8; ++j)
                    a[j] = (short)f2bf(xv[j] * p);
            }
            int byteoff = row * 256 + ((chunk * 16) ^ ((row & 7) << 4)); // XOR swizzle
            *reinterpret_cast<short8*>(reinterpret_cast<char*>(A_lds) + byteoff) = a;
        }
        __syncthreads();

        f32x4 acc0 = {0.f, 0.f, 0.f, 0.f};
        f32x4 acc1 = {0.f, 0.f, 0.f, 0.f};
        #pragma unroll
        for (int kk = 0; kk < 4; ++kk) {
            // A-frag: row = lane&15, k = kk*32 + 8*(lane>>4) + v -> 16B contiguous.
            int row = lane_lo;
            int byteoff = row * 256 + ((kk * 64 + lane_hi * 16) ^ ((row & 7) << 4));
            short8 a = *reinterpret_cast<const short8*>(
                reinterpret_cast<char*>(A_lds) + byteoff);
            acc0 = __builtin_amdgcn_mfma_f32_16x16x32_bf16(a, bw[kk][0], acc0, 0, 0, 0);
            acc1 = __builtin_amdgcn_mfma_f32_16x16x32_bf16(a, bw[kk][1], acc1, 0, 0, 0);
        }

        // Epilogue: D[row][col], col = lane&15, row = 4*(lane>>4)+v.
        // Write this slot's proj row slice -- exclusively owned, no atomics.
        #pragma unroll
        for (int v = 0; v < 4; ++v) {
            int row = lane_hi * 4 + v;
            int slot = slots_lds[row];
            if (slot >= 0) {
                unsigned short* pr = proj + (size_t)slot * DMODEL + mw;
                pr[lane_lo]      = f2bf(acc0[v]);
                pr[16 + lane_lo] = f2bf(acc1[v]);
            }
        }
    }
}

// Merge: out[tok][m] = sum_k proj[tok*4+k][m] + p_k * bias[sel_k][m].
// 2048 blocks x 256 threads; thread owns 8 consecutive m-columns (32B).
// Pure coalesced streaming, no atomics; fully overwrites out (no memset).
__global__ void merge_kernel(const unsigned short* __restrict__ proj,
                             const int* __restrict__ sel,
                             const float* __restrict__ probs,
                             const float* __restrict__ bias,
                             float* __restrict__ out) {
    int tid = threadIdx.x;
    int tok = blockIdx.x;
    float8 acc = {0.f, 0.f, 0.f, 0.f, 0.f, 0.f, 0.f, 0.f};
    #pragma unroll
    for (int k = 0; k < 4; ++k) {
        int slot = tok * 4 + k;
        short8 pr = reinterpret_cast<const short8*>(proj + (size_t)slot * DMODEL)[tid];
        float p = probs[slot];
        int bk = sel[slot];
        float8 bv = reinterpret_cast<const float8*>(bias + (size_t)bk * DMODEL)[tid];
        #pragma unroll
        for (int j = 0; j < 8; ++j)
            acc[j] += bf2f((unsigned short)pr[j]) + p * bv[j];
    }
    reinterpret_cast<float8*>(out + (size_t)tok * DMODEL)[tid] = acc;
}

extern "C" void kernel_launch(void* const* d_in, const int* in_sizes, int n_in,
                              void* d_out, int out_size, void* d_ws, size_t ws_size,
                              hipStream_t stream) {
    const float* x     = (const float*)d_in[0];  // (2,1024,4,128)
    const int*   sel   = (const int*)  d_in[1];  // (2,1024,4)
    const float* probs = (const float*)d_in[2];  // (2,1024,4)
    const float* W     = (const float*)d_in[3];  // (32,128,2048)
    const float* bias  = (const float*)d_in[4];  // (32,2048)
    float* out = (float*)d_out;                  // (2,1024,2048) fp32

    // ws layout (~51 MB):
    //   [0,128)                    counts (32 ints, zeroed each call)
    //   [1024, 1049600)            lists  (32 x 8192 ints)
    //   [2MB,  2MB+16.8MB)         wfrag  (32x128x2048 bf16, fragment-swizzled)
    //   [19MB, 19MB+33.5MB)        proj   (8192 x 2048 bf16)
    char* ws = (char*)d_ws;
    int* counts = (int*)ws;
    int* lists  = (int*)(ws + 1024);
    unsigned short* wfrag = (unsigned short*)(ws + (2u << 20));
    unsigned short* proj  = (unsigned short*)(ws + (19u << 20));

    hipMemsetAsync(counts, 0, 128, stream);
    convW_kernel<<<4096, 256, 0, stream>>>(W, wfrag);
    bucket_kernel<<<32, 256, 0, stream>>>(sel, counts, lists);
    gemm_kernel<<<dim3(16, 32, 4), 256, 0, stream>>>(wfrag, x, counts, lists,
                                                     probs, proj);
    merge_kernel<<<2048, 256, 0, stream>>>(proj, sel, probs, bias, out);
}